// Round 11
// baseline (351.520 us; speedup 1.0000x reference)
//
#include <hip/hip_runtime.h>
#include <hip/hip_fp16.h>

#define N_NODES 100000
#define IN_CH 2048
#define OUT_CH 128
#define NNZ_FEAT 2000000
#define NNZ_ADJ 1600000
#define NNZ_TOT (NNZ_FEAT + NNZ_ADJ)
#define BROWS 512                      // rows per bucket
#define NBUCK 391                      // ceil(200000 / 512)
#define NROWP (NBUCK * BROWS)          // 200192 padded row-count length
#define KB_BLOCK 256
#define KB_ITEMS 8
#define KB_CHUNK (KB_BLOCK * KB_ITEMS) // 2048
#define KB_GRID ((NNZ_TOT + KB_CHUNK - 1) / KB_CHUNK)  // 1758

// pack: (row_in_bucket << 17) | col     (col < 131072, rib < 512)
#define PK_COL_BITS 17
#define PK_COL_MASK ((1 << PK_COL_BITS) - 1)

// ---------------- stage A: bucket histogram (LDS-aggregated) ----------------

__global__ __launch_bounds__(KB_BLOCK) void kA(const int* __restrict__ frows,
                                               const int* __restrict__ arows,
                                               int* __restrict__ bcnt) {
    __shared__ int hist[NBUCK];
    for (int t = threadIdx.x; t < NBUCK; t += KB_BLOCK) hist[t] = 0;
    __syncthreads();
    long base = (long)blockIdx.x * KB_CHUNK;
    for (int j = 0; j < KB_ITEMS; ++j) {
        long i = base + j * KB_BLOCK + threadIdx.x;
        if (i < NNZ_TOT) {
            int r = (i < NNZ_FEAT) ? frows[i] : (N_NODES + arows[i - NNZ_FEAT]);
            atomicAdd(&hist[r >> 9], 1);
        }
    }
    __syncthreads();
    for (int t = threadIdx.x; t < NBUCK; t += KB_BLOCK)
        if (hist[t]) atomicAdd(&bcnt[t], hist[t]);
}

// scan 391 bucket counts in one block of 512; emit boff (exclusive) and gcur copy
__global__ void k_scanb(const int* __restrict__ bcnt, int* __restrict__ boff,
                        int* __restrict__ gcur) {
    __shared__ int s[512];
    int t = threadIdx.x;
    int v = (t < NBUCK) ? bcnt[t] : 0;
    s[t] = v;
    __syncthreads();
    for (int off = 1; off < 512; off <<= 1) {
        int x = (t >= off) ? s[t - off] : 0;
        __syncthreads();
        s[t] += x;
        __syncthreads();
    }
    int e = s[t] - v;
    if (t < NBUCK) { boff[t] = e; gcur[t] = e; }
    if (t == NBUCK - 1) boff[NBUCK] = s[t];
}

// ---------------- stage B: LDS bucket-sort then item-parallel coalesced flush ----

__global__ __launch_bounds__(KB_BLOCK) void kB(const int* __restrict__ frows,
                                               const int* __restrict__ fcols,
                                               const float* __restrict__ fvals,
                                               const int* __restrict__ arows,
                                               const int* __restrict__ acols,
                                               const float* __restrict__ avals,
                                               int* __restrict__ gcur,
                                               int* __restrict__ tmp_pk,
                                               float* __restrict__ tmp_vl) {
    __shared__ int hist[NBUCK];
    __shared__ int lcnt[NBUCK];
    __shared__ int gb[NBUCK];
    __shared__ int bstart[NBUCK];
    __shared__ int sc[512];
    __shared__ int s_pk[KB_CHUNK];
    __shared__ float s_vl[KB_CHUNK];
    __shared__ unsigned short s_bid[KB_CHUNK];

    int tid = threadIdx.x;
    for (int t = tid; t < NBUCK; t += KB_BLOCK) { hist[t] = 0; lcnt[t] = 0; }
    __syncthreads();

    long base = (long)blockIdx.x * KB_CHUNK;
    int rr[KB_ITEMS];
    for (int j = 0; j < KB_ITEMS; ++j) {
        long i = base + j * KB_BLOCK + tid;
        int r = -1;
        if (i < NNZ_TOT) {
            r = (i < NNZ_FEAT) ? frows[i] : (N_NODES + arows[i - NNZ_FEAT]);
            atomicAdd(&hist[r >> 9], 1);
        }
        rr[j] = r;
    }
    __syncthreads();

    // inclusive scan of hist (padded to 512) with 256 threads handling 2 each
    sc[tid] = (tid < NBUCK) ? hist[tid] : 0;
    sc[tid + 256] = (tid + 256 < NBUCK) ? hist[tid + 256] : 0;
    __syncthreads();
    for (int o = 1; o < 512; o <<= 1) {
        int a0 = (tid >= o) ? sc[tid - o] : 0;
        int a1 = ((tid + 256) >= o) ? sc[tid + 256 - o] : 0;
        __syncthreads();
        sc[tid] += a0;
        sc[tid + 256] += a1;
        __syncthreads();
    }
    for (int t = tid; t < NBUCK; t += KB_BLOCK) {
        int h = hist[t];
        bstart[t] = sc[t] - h;                       // exclusive LDS start
        gb[t] = h ? atomicAdd(&gcur[t], h) : 0;      // reserve global run
    }
    __syncthreads();
    int tot = sc[NBUCK - 1];                         // items in this block

    // place items into LDS at bucket-sorted slots (record bucket id per slot)
    for (int j = 0; j < KB_ITEMS; ++j) {
        int r = rr[j];
        if (r >= 0) {
            long i = base + j * KB_BLOCK + tid;
            int c; float v;
            if (i < NNZ_FEAT) { c = fcols[i]; v = fvals[i]; }
            else              { c = acols[i - NNZ_FEAT]; v = avals[i - NNZ_FEAT]; }
            int b = r >> 9;
            int slot = bstart[b] + atomicAdd(&lcnt[b], 1);
            s_pk[slot] = ((r & 511) << PK_COL_BITS) | c;
            s_vl[slot] = v;
            s_bid[slot] = (unsigned short)b;
        }
    }
    __syncthreads();

    // item-parallel flush: consecutive slots -> consecutive global addresses
    for (int s = tid; s < tot; s += KB_BLOCK) {
        int b = s_bid[s];
        int dest = gb[b] + (s - bstart[b]);
        tmp_pk[dest] = s_pk[s];
        tmp_vl[dest] = s_vl[s];
    }
}

// ---------------- stage C (fused): count rows, in-bucket scan -> S, place ------

__global__ __launch_bounds__(256) void kC(const int* __restrict__ boff,
                                          const int* __restrict__ tmp_pk,
                                          const float* __restrict__ tmp_vl,
                                          int2* __restrict__ pairs,
                                          int* __restrict__ S) {
    __shared__ int rcnt[BROWS];
    __shared__ int sc2[BROWS];
    __shared__ int rcur[BROWS];
    int tid = threadIdx.x;
    int b = blockIdx.x, rbase = b << 9;
    rcnt[tid] = 0;
    rcnt[tid + 256] = 0;
    __syncthreads();
    int e0 = boff[b], e1 = boff[b + 1];
    for (int i = e0 + tid; i < e1; i += 256)
        atomicAdd(&rcnt[tmp_pk[i] >> PK_COL_BITS], 1);
    __syncthreads();
    // inclusive scan of 512 row counts with 256 threads
    sc2[tid] = rcnt[tid];
    sc2[tid + 256] = rcnt[tid + 256];
    __syncthreads();
    for (int o = 1; o < 512; o <<= 1) {
        int a0 = (tid >= o) ? sc2[tid - o] : 0;
        int a1 = ((tid + 256) >= o) ? sc2[tid + 256 - o] : 0;
        __syncthreads();
        sc2[tid] += a0;
        sc2[tid + 256] += a1;
        __syncthreads();
    }
    int ex0 = e0 + sc2[tid] - rcnt[tid];
    int ex1 = e0 + sc2[tid + 256] - rcnt[tid + 256];
    S[rbase + tid] = ex0;
    S[rbase + tid + 256] = ex1;
    rcur[tid] = ex0;
    rcur[tid + 256] = ex1;
    __syncthreads();
    for (int i = e0 + tid; i < e1; i += 256) {
        int pk = tmp_pk[i];
        float v = tmp_vl[i];
        int p = atomicAdd(&rcur[pk >> PK_COL_BITS], 1);
        pairs[p] = make_int2(pk & PK_COL_MASK, __float_as_int(v));
    }
}

// ---------------- W fp32 -> fp16 ----------------

__global__ __launch_bounds__(256) void k_wconv(const float* __restrict__ W,
                                               __half2* __restrict__ Wh) {
    int i = blockIdx.x * 256 + threadIdx.x;
    if (i < IN_CH * OUT_CH / 2) {
        float2 f = ((const float2*)W)[i];
        Wh[i] = __floats2half2_rn(f.x, f.y);
    }
}

// ---------------- SpMM kernels ----------------
// wave per row; lane l preloads pairs[k0+l] for a 64-chunk; (col,val) broadcast
// via readlane -> gathers are SGPR-base loads with no inter-load dependency.
// 16-deep unrolled groups: 16 independent gathers in flight per wave.
// Each lane handles 2 channels packed in __half2 (128 ch total).

#define SPMM_GROUP(OFS)                                                        \
    _Pragma("unroll")                                                          \
    for (int j = 0; j < 16; ++j) {                                             \
        int c = __builtin_amdgcn_readlane(pp.x, (OFS) + j);                    \
        float v = __int_as_float(__builtin_amdgcn_readlane(pp.y, (OFS) + j));  \
        float2 f = __half22float2(HSRC_AT(c));                                 \
        if (j & 1) { a1.x = fmaf(v, f.x, a1.x); a1.y = fmaf(v, f.y, a1.y); }   \
        else       { a0.x = fmaf(v, f.x, a0.x); a0.y = fmaf(v, f.y, a0.y); }   \
    }

#define SPMM_BODY(ACC_INIT)                                                    \
    int row = blockIdx.x * 4 + (threadIdx.x >> 6);                             \
    int lane = threadIdx.x & 63;                                               \
    int k0 = __builtin_amdgcn_readfirstlane(SROW0);                            \
    int k1 = __builtin_amdgcn_readfirstlane(SROW1);                            \
    float2 a0 = ACC_INIT;                                                      \
    float2 a1 = make_float2(0.0f, 0.0f);                                       \
    for (int base = k0; base < k1; base += 64) {                               \
        int idx = base + lane;                                                 \
        int2 pp = (idx < k1) ? pairs[idx] : make_int2(0, 0);                   \
        int n = k1 - base; if (n > 64) n = 64;                                 \
        int full = n & ~15;                                                    \
        for (int jj = 0; jj < full; jj += 16) { SPMM_GROUP(jj) }               \
        if (full < n) { SPMM_GROUP(full) }                                     \
    }

// h0 = relu(F*Wh + b), output fp16
__global__ __launch_bounds__(256) void spmm_w(const int* __restrict__ S,
                                              const int2* __restrict__ pairs,
                                              const __half2* __restrict__ Wh,
                                              const float* __restrict__ bias,
                                              __half2* __restrict__ out16) {
#define SROW0 S[row]
#define SROW1 S[row + 1]
#define HSRC_AT(c) Wh[(size_t)(c) * (OUT_CH / 2) + lane]
    SPMM_BODY(((const float2*)bias)[lane])
#undef HSRC_AT
#undef SROW0
#undef SROW1
    float rx = fmaxf(a0.x + a1.x, 0.0f);
    float ry = fmaxf(a0.y + a1.y, 0.0f);
    out16[(size_t)row * (OUT_CH / 2) + lane] = __floats2half2_rn(rx, ry);
}

// h = A*h, fp16 in -> fp16 out
__global__ __launch_bounds__(256) void spmm_adj_hh(const int* __restrict__ S,
                                                   const int2* __restrict__ pairs,
                                                   const __half2* __restrict__ hin,
                                                   __half2* __restrict__ hout) {
#define SROW0 S[N_NODES + row]
#define SROW1 S[N_NODES + row + 1]
#define HSRC_AT(c) hin[(size_t)(c) * (OUT_CH / 2) + lane]
    SPMM_BODY(make_float2(0.0f, 0.0f))
#undef HSRC_AT
#undef SROW0
#undef SROW1
    hout[(size_t)row * (OUT_CH / 2) + lane] = __floats2half2_rn(a0.x + a1.x, a0.y + a1.y);
}

// final hop: fp16 in -> fp32 out (d_out)
__global__ __launch_bounds__(256) void spmm_adj_hf(const int* __restrict__ S,
                                                   const int2* __restrict__ pairs,
                                                   const __half2* __restrict__ hin,
                                                   float* __restrict__ out) {
#define SROW0 S[N_NODES + row]
#define SROW1 S[N_NODES + row + 1]
#define HSRC_AT(c) hin[(size_t)(c) * (OUT_CH / 2) + lane]
    SPMM_BODY(make_float2(0.0f, 0.0f))
#undef HSRC_AT
#undef SROW0
#undef SROW1
    float2 acc;
    acc.x = a0.x + a1.x;
    acc.y = a0.y + a1.y;
    ((float2*)(out + (size_t)row * OUT_CH))[lane] = acc;
}

// ---------------- driver ----------------

extern "C" void kernel_launch(void* const* d_in, const int* in_sizes, int n_in,
                              void* d_out, int out_size, void* d_ws, size_t ws_size,
                              hipStream_t stream) {
    const int*   frows = (const int*)d_in[0];
    const int*   fcols = (const int*)d_in[1];
    const float* fvals = (const float*)d_in[2];
    const int*   arows = (const int*)d_in[3];
    const int*   acols = (const int*)d_in[4];
    const float* avals = (const float*)d_in[5];
    const float* W     = (const float*)d_in[6];
    const float* bias  = (const float*)d_in[7];
    float* out = (float*)d_out;

    char* ws = (char*)d_ws;
    size_t off = 0;
    auto alloc = [&](size_t bytes) {
        size_t o = off;
        off = (off + bytes + 255) & ~(size_t)255;
        return o;
    };
    int*  S     = (int*) (ws + alloc((size_t)NROWP * 4));
    int*  bcnt  = (int*) (ws + alloc(400 * 4));
    int*  boff  = (int*) (ws + alloc(400 * 4));
    int*  gcur  = (int*) (ws + alloc(400 * 4));
    int2* pairs = (int2*)(ws + alloc((size_t)NNZ_TOT * 8));
    __half2* Wh = (__half2*)(ws + alloc((size_t)IN_CH * OUT_CH * 2));
    char* hraw  = ws + alloc(2 * (size_t)N_NODES * OUT_CH * 2);   // two fp16 h buffers
    __half2* hA = (__half2*)hraw;
    __half2* hB = (__half2*)(hraw + (size_t)N_NODES * OUT_CH * 2);
    // tmp buffers alias onto hA/hB region: dead before spmm_w runs
    int*   tmp_pk = (int*)hraw;                                         // 14.4 MB
    float* tmp_vl = (float*)(hraw + (((size_t)NNZ_TOT * 4 + 255) & ~(size_t)255)); // 14.4 MB
    (void)ws_size; (void)off; (void)in_sizes; (void)n_in; (void)out_size;

    hipMemsetAsync(bcnt, 0, 400 * 4, stream);
    k_wconv<<<(IN_CH * OUT_CH / 2 + 255) / 256, 256, 0, stream>>>(W, Wh);
    kA<<<KB_GRID, KB_BLOCK, 0, stream>>>(frows, arows, bcnt);
    k_scanb<<<1, 512, 0, stream>>>(bcnt, boff, gcur);
    kB<<<KB_GRID, KB_BLOCK, 0, stream>>>(frows, fcols, fvals, arows, acols, avals,
                                         gcur, tmp_pk, tmp_vl);
    kC<<<NBUCK, 256, 0, stream>>>(boff, tmp_pk, tmp_vl, pairs, S);

    spmm_w<<<N_NODES / 4, 256, 0, stream>>>(S, pairs, Wh, bias, hA);

    spmm_adj_hh<<<N_NODES / 4, 256, 0, stream>>>(S, pairs, hA, hB);
    spmm_adj_hh<<<N_NODES / 4, 256, 0, stream>>>(S, pairs, hB, hA);
    spmm_adj_hf<<<N_NODES / 4, 256, 0, stream>>>(S, pairs, hA, out);
}

// Round 12
// 307.957 us; speedup vs baseline: 1.1415x; 1.1415x over previous
//
#include <hip/hip_runtime.h>
#include <hip/hip_fp16.h>

#define N_NODES 100000
#define IN_CH 2048
#define OUT_CH 128
#define NNZ_FEAT 2000000
#define NNZ_ADJ 1600000
#define NNZ_TOT (NNZ_FEAT + NNZ_ADJ)
#define BROWS 512                      // rows per bucket
#define NBUCK 391                      // ceil(200000 / 512)
#define NROWP (NBUCK * BROWS)          // 200192 padded row-count length
#define BCAP 12288                     // fixed tmp slots per bucket (>20 sigma)
#define KB_BLOCK 256
#define KB_ITEMS 16
#define KB_CHUNK (KB_BLOCK * KB_ITEMS) // 4096
#define KB_GRID ((NNZ_TOT + KB_CHUNK - 1) / KB_CHUNK)  // 879

// pack: (row_in_bucket << 17) | col     (col < 131072, rib < 512)
#define PK_COL_BITS 17
#define PK_COL_MASK ((1 << PK_COL_BITS) - 1)

// ---------------- init: gcur[b] = b * BCAP ----------------

__global__ void k_init(int* __restrict__ gcur) {
    int t = threadIdx.x;
    if (t < NBUCK) gcur[t] = t * BCAP;
}

// ---------------- stage B: LDS bucket-sort then item-parallel coalesced flush ----
// scatter into FIXED per-bucket regions of tmp (no global histogram needed)

__global__ __launch_bounds__(KB_BLOCK) void kB(const int* __restrict__ frows,
                                               const int* __restrict__ fcols,
                                               const float* __restrict__ fvals,
                                               const int* __restrict__ arows,
                                               const int* __restrict__ acols,
                                               const float* __restrict__ avals,
                                               int* __restrict__ gcur,
                                               int* __restrict__ tmp_pk,
                                               float* __restrict__ tmp_vl) {
    __shared__ int hist[NBUCK];
    __shared__ int lcnt[NBUCK];
    __shared__ int gb[NBUCK];
    __shared__ int bstart[NBUCK];
    __shared__ int sc[512];
    __shared__ int s_pk[KB_CHUNK];
    __shared__ float s_vl[KB_CHUNK];
    __shared__ unsigned short s_bid[KB_CHUNK];

    int tid = threadIdx.x;
    for (int t = tid; t < NBUCK; t += KB_BLOCK) { hist[t] = 0; lcnt[t] = 0; }
    __syncthreads();

    long base = (long)blockIdx.x * KB_CHUNK;
    int rr[KB_ITEMS];
    for (int j = 0; j < KB_ITEMS; ++j) {
        long i = base + j * KB_BLOCK + tid;
        int r = -1;
        if (i < NNZ_TOT) {
            r = (i < NNZ_FEAT) ? frows[i] : (N_NODES + arows[i - NNZ_FEAT]);
            atomicAdd(&hist[r >> 9], 1);
        }
        rr[j] = r;
    }
    __syncthreads();

    // inclusive scan of hist (padded to 512) with 256 threads handling 2 each
    sc[tid] = (tid < NBUCK) ? hist[tid] : 0;
    sc[tid + 256] = (tid + 256 < NBUCK) ? hist[tid + 256] : 0;
    __syncthreads();
    for (int o = 1; o < 512; o <<= 1) {
        int a0 = (tid >= o) ? sc[tid - o] : 0;
        int a1 = ((tid + 256) >= o) ? sc[tid + 256 - o] : 0;
        __syncthreads();
        sc[tid] += a0;
        sc[tid + 256] += a1;
        __syncthreads();
    }
    for (int t = tid; t < NBUCK; t += KB_BLOCK) {
        int h = hist[t];
        bstart[t] = sc[t] - h;                       // exclusive LDS start
        gb[t] = h ? atomicAdd(&gcur[t], h) : 0;      // reserve run in fixed region
    }
    __syncthreads();
    int tot = sc[NBUCK - 1];                         // items in this block

    // place items into LDS at bucket-sorted slots (record bucket id per slot)
    for (int j = 0; j < KB_ITEMS; ++j) {
        int r = rr[j];
        if (r >= 0) {
            long i = base + j * KB_BLOCK + tid;
            int c; float v;
            if (i < NNZ_FEAT) { c = fcols[i]; v = fvals[i]; }
            else              { c = acols[i - NNZ_FEAT]; v = avals[i - NNZ_FEAT]; }
            int b = r >> 9;
            int slot = bstart[b] + atomicAdd(&lcnt[b], 1);
            s_pk[slot] = ((r & 511) << PK_COL_BITS) | c;
            s_vl[slot] = v;
            s_bid[slot] = (unsigned short)b;
        }
    }
    __syncthreads();

    // item-parallel flush: consecutive slots -> consecutive global addresses
    for (int s = tid; s < tot; s += KB_BLOCK) {
        int b = s_bid[s];
        int dest = gb[b] + (s - bstart[b]);
        tmp_pk[dest] = s_pk[s];
        tmp_vl[dest] = s_vl[s];
    }
}

// ---------------- scan bucket counts -> dense CSR bucket starts ----------------

__global__ void k_scand(const int* __restrict__ gcur, int* __restrict__ dstart) {
    __shared__ int s[512];
    int t = threadIdx.x;
    int cnt = (t < NBUCK) ? (gcur[t] - t * BCAP) : 0;
    s[t] = cnt;
    __syncthreads();
    for (int o = 1; o < 512; o <<= 1) {
        int x = (t >= o) ? s[t - o] : 0;
        __syncthreads();
        s[t] += x;
        __syncthreads();
    }
    if (t < NBUCK) dstart[t] = s[t] - cnt;           // exclusive
}

// ---------------- stage C (fused): count rows, in-bucket scan -> S, place ------

__global__ __launch_bounds__(256) void kC(const int* __restrict__ gcur,
                                          const int* __restrict__ dstart,
                                          const int* __restrict__ tmp_pk,
                                          const float* __restrict__ tmp_vl,
                                          int2* __restrict__ pairs,
                                          int* __restrict__ S) {
    __shared__ int rcnt[BROWS];
    __shared__ int sc2[BROWS];
    __shared__ int rcur[BROWS];
    int tid = threadIdx.x;
    int b = blockIdx.x, rbase = b << 9;
    rcnt[tid] = 0;
    rcnt[tid + 256] = 0;
    __syncthreads();
    int e0 = b * BCAP;
    int e1 = e0 + (gcur[b] - b * BCAP);
    int dbase = dstart[b];
    for (int i = e0 + tid; i < e1; i += 256)
        atomicAdd(&rcnt[tmp_pk[i] >> PK_COL_BITS], 1);
    __syncthreads();
    // inclusive scan of 512 row counts with 256 threads
    sc2[tid] = rcnt[tid];
    sc2[tid + 256] = rcnt[tid + 256];
    __syncthreads();
    for (int o = 1; o < 512; o <<= 1) {
        int a0 = (tid >= o) ? sc2[tid - o] : 0;
        int a1 = ((tid + 256) >= o) ? sc2[tid + 256 - o] : 0;
        __syncthreads();
        sc2[tid] += a0;
        sc2[tid + 256] += a1;
        __syncthreads();
    }
    int ex0 = dbase + sc2[tid] - rcnt[tid];
    int ex1 = dbase + sc2[tid + 256] - rcnt[tid + 256];
    S[rbase + tid] = ex0;
    S[rbase + tid + 256] = ex1;
    rcur[tid] = ex0;
    rcur[tid + 256] = ex1;
    __syncthreads();
    for (int i = e0 + tid; i < e1; i += 256) {
        int pk = tmp_pk[i];
        float v = tmp_vl[i];
        int p = atomicAdd(&rcur[pk >> PK_COL_BITS], 1);
        pairs[p] = make_int2(pk & PK_COL_MASK, __float_as_int(v));
    }
}

// ---------------- W fp32 -> fp16 ----------------

__global__ __launch_bounds__(256) void k_wconv(const float* __restrict__ W,
                                               __half2* __restrict__ Wh) {
    int i = blockIdx.x * 256 + threadIdx.x;
    if (i < IN_CH * OUT_CH / 2) {
        float2 f = ((const float2*)W)[i];
        Wh[i] = __floats2half2_rn(f.x, f.y);
    }
}

// ---------------- SpMM kernels ----------------
// wave per row; lane l preloads pairs[k0+l] for a 64-chunk; (col,val) broadcast
// via readlane -> gathers are SGPR-base loads with no inter-load dependency.
// 8-deep groups (R10 sweet spot). Each lane: 2 channels packed in __half2.

#define SPMM_GROUP(OFS)                                                        \
    _Pragma("unroll")                                                          \
    for (int j = 0; j < 8; ++j) {                                              \
        int c = __builtin_amdgcn_readlane(pp.x, (OFS) + j);                    \
        float v = __int_as_float(__builtin_amdgcn_readlane(pp.y, (OFS) + j));  \
        float2 f = __half22float2(HSRC_AT(c));                                 \
        if (j & 1) { a1.x = fmaf(v, f.x, a1.x); a1.y = fmaf(v, f.y, a1.y); }   \
        else       { a0.x = fmaf(v, f.x, a0.x); a0.y = fmaf(v, f.y, a0.y); }   \
    }

#define SPMM_BODY(ACC_INIT)                                                    \
    int row = blockIdx.x * 4 + (threadIdx.x >> 6);                             \
    int lane = threadIdx.x & 63;                                               \
    int k0 = __builtin_amdgcn_readfirstlane(SROW0);                            \
    int k1 = __builtin_amdgcn_readfirstlane(SROW1);                            \
    float2 a0 = ACC_INIT;                                                      \
    float2 a1 = make_float2(0.0f, 0.0f);                                       \
    for (int base = k0; base < k1; base += 64) {                               \
        int idx = base + lane;                                                 \
        int2 pp = (idx < k1) ? pairs[idx] : make_int2(0, 0);                   \
        int n = k1 - base; if (n > 64) n = 64;                                 \
        int full = n & ~7;                                                     \
        for (int jj = 0; jj < full; jj += 8) { SPMM_GROUP(jj) }                \
        if (full < n) { SPMM_GROUP(full) }                                     \
    }

// h0 = relu(F*Wh + b), output fp16
__global__ __launch_bounds__(256) void spmm_w(const int* __restrict__ S,
                                              const int2* __restrict__ pairs,
                                              const __half2* __restrict__ Wh,
                                              const float* __restrict__ bias,
                                              __half2* __restrict__ out16) {
#define SROW0 S[row]
#define SROW1 S[row + 1]
#define HSRC_AT(c) Wh[(size_t)(c) * (OUT_CH / 2) + lane]
    SPMM_BODY(((const float2*)bias)[lane])
#undef HSRC_AT
#undef SROW0
#undef SROW1
    float rx = fmaxf(a0.x + a1.x, 0.0f);
    float ry = fmaxf(a0.y + a1.y, 0.0f);
    out16[(size_t)row * (OUT_CH / 2) + lane] = __floats2half2_rn(rx, ry);
}

// h = A*h, fp16 in -> fp16 out
__global__ __launch_bounds__(256) void spmm_adj_hh(const int* __restrict__ S,
                                                   const int2* __restrict__ pairs,
                                                   const __half2* __restrict__ hin,
                                                   __half2* __restrict__ hout) {
#define SROW0 S[N_NODES + row]
#define SROW1 S[N_NODES + row + 1]
#define HSRC_AT(c) hin[(size_t)(c) * (OUT_CH / 2) + lane]
    SPMM_BODY(make_float2(0.0f, 0.0f))
#undef HSRC_AT
#undef SROW0
#undef SROW1
    hout[(size_t)row * (OUT_CH / 2) + lane] = __floats2half2_rn(a0.x + a1.x, a0.y + a1.y);
}

// final hop: fp16 in -> fp32 out (d_out)
__global__ __launch_bounds__(256) void spmm_adj_hf(const int* __restrict__ S,
                                                   const int2* __restrict__ pairs,
                                                   const __half2* __restrict__ hin,
                                                   float* __restrict__ out) {
#define SROW0 S[N_NODES + row]
#define SROW1 S[N_NODES + row + 1]
#define HSRC_AT(c) hin[(size_t)(c) * (OUT_CH / 2) + lane]
    SPMM_BODY(make_float2(0.0f, 0.0f))
#undef HSRC_AT
#undef SROW0
#undef SROW1
    float2 acc;
    acc.x = a0.x + a1.x;
    acc.y = a0.y + a1.y;
    ((float2*)(out + (size_t)row * OUT_CH))[lane] = acc;
}

// ---------------- driver ----------------

extern "C" void kernel_launch(void* const* d_in, const int* in_sizes, int n_in,
                              void* d_out, int out_size, void* d_ws, size_t ws_size,
                              hipStream_t stream) {
    const int*   frows = (const int*)d_in[0];
    const int*   fcols = (const int*)d_in[1];
    const float* fvals = (const float*)d_in[2];
    const int*   arows = (const int*)d_in[3];
    const int*   acols = (const int*)d_in[4];
    const float* avals = (const float*)d_in[5];
    const float* W     = (const float*)d_in[6];
    const float* bias  = (const float*)d_in[7];
    float* out = (float*)d_out;

    char* ws = (char*)d_ws;
    size_t off = 0;
    auto alloc = [&](size_t bytes) {
        size_t o = off;
        off = (off + bytes + 255) & ~(size_t)255;
        return o;
    };
    int*  S      = (int*) (ws + alloc((size_t)NROWP * 4));
    int*  gcur   = (int*) (ws + alloc(512 * 4));
    int*  dstart = (int*) (ws + alloc(512 * 4));
    int2* pairs  = (int2*)(ws + alloc((size_t)NNZ_TOT * 8));
    __half2* Wh  = (__half2*)(ws + alloc((size_t)IN_CH * OUT_CH * 2));
    char* hraw   = ws + alloc(2 * (size_t)N_NODES * OUT_CH * 2);   // two fp16 h buffers
    __half2* hA  = (__half2*)hraw;
    __half2* hB  = (__half2*)(hraw + (size_t)N_NODES * OUT_CH * 2);
    // tmp buffers alias onto hA/hB region (51.2 MB): dead before spmm_w runs
    int*   tmp_pk = (int*)hraw;                                          // 19.2 MB
    float* tmp_vl = (float*)(hraw + (((size_t)NBUCK * BCAP * 4 + 255) & ~(size_t)255)); // 19.2 MB
    (void)ws_size; (void)off; (void)in_sizes; (void)n_in; (void)out_size;

    k_init<<<1, 512, 0, stream>>>(gcur);
    k_wconv<<<(IN_CH * OUT_CH / 2 + 255) / 256, 256, 0, stream>>>(W, Wh);
    kB<<<KB_GRID, KB_BLOCK, 0, stream>>>(frows, fcols, fvals, arows, acols, avals,
                                         gcur, tmp_pk, tmp_vl);
    k_scand<<<1, 512, 0, stream>>>(gcur, dstart);
    kC<<<NBUCK, 256, 0, stream>>>(gcur, dstart, tmp_pk, tmp_vl, pairs, S);

    spmm_w<<<N_NODES / 4, 256, 0, stream>>>(S, pairs, Wh, bias, hA);

    spmm_adj_hh<<<N_NODES / 4, 256, 0, stream>>>(S, pairs, hA, hB);
    spmm_adj_hh<<<N_NODES / 4, 256, 0, stream>>>(S, pairs, hB, hA);
    spmm_adj_hf<<<N_NODES / 4, 256, 0, stream>>>(S, pairs, hA, out);
}

// Round 13
// 294.921 us; speedup vs baseline: 1.1919x; 1.0442x over previous
//
#include <hip/hip_runtime.h>
#include <hip/hip_fp16.h>

#define N_NODES 100000
#define IN_CH 2048
#define OUT_CH 128
#define NNZ_FEAT 2000000
#define NNZ_ADJ 1600000
#define NNZ_TOT (NNZ_FEAT + NNZ_ADJ)
#define BROWS 512                      // rows per bucket
#define NBUCK 391                      // ceil(200000 / 512)
#define NROWP (NBUCK * BROWS)          // 200192 padded row-count length
#define BCAP 12288                     // fixed tmp slots per bucket (>20 sigma)
#define KB_BLOCK 512
#define KB_ITEMS 8
#define KB_CHUNK (KB_BLOCK * KB_ITEMS) // 4096
#define KB_GRID ((NNZ_TOT + KB_CHUNK - 1) / KB_CHUNK)  // 879

// pack: (row_in_bucket << 17) | col     (col < 131072, rib < 512)
#define PK_COL_BITS 17
#define PK_COL_MASK ((1 << PK_COL_BITS) - 1)

// ---------------- init: gcur[b] = b * BCAP ----------------

__global__ void k_init(int* __restrict__ gcur) {
    int t = threadIdx.x;
    if (t < NBUCK) gcur[t] = t * BCAP;
}

// ---------------- stage B: LDS bucket-sort then item-parallel coalesced flush ----
// scatter into FIXED per-bucket regions of tmp (no global histogram needed)
// 512 threads (8 waves) per block for latency hiding; chunk stays 4096.

__global__ __launch_bounds__(KB_BLOCK) void kB(const int* __restrict__ frows,
                                               const int* __restrict__ fcols,
                                               const float* __restrict__ fvals,
                                               const int* __restrict__ arows,
                                               const int* __restrict__ acols,
                                               const float* __restrict__ avals,
                                               int* __restrict__ gcur,
                                               int* __restrict__ tmp_pk,
                                               float* __restrict__ tmp_vl) {
    __shared__ int hist[NBUCK];
    __shared__ int lcnt[NBUCK];
    __shared__ int gb[NBUCK];
    __shared__ int bstart[NBUCK];
    __shared__ int sc[512];
    __shared__ int s_pk[KB_CHUNK];
    __shared__ float s_vl[KB_CHUNK];
    __shared__ unsigned short s_bid[KB_CHUNK];

    int tid = threadIdx.x;
    if (tid < NBUCK) { hist[tid] = 0; lcnt[tid] = 0; }
    __syncthreads();

    long base = (long)blockIdx.x * KB_CHUNK;
    int rr[KB_ITEMS];
    for (int j = 0; j < KB_ITEMS; ++j) {
        long i = base + j * KB_BLOCK + tid;
        int r = -1;
        if (i < NNZ_TOT) {
            r = (i < NNZ_FEAT) ? frows[i] : (N_NODES + arows[i - NNZ_FEAT]);
            atomicAdd(&hist[r >> 9], 1);
        }
        rr[j] = r;
    }
    __syncthreads();

    // inclusive scan of hist (padded to 512), one element per thread
    sc[tid] = (tid < NBUCK) ? hist[tid] : 0;
    __syncthreads();
    for (int o = 1; o < 512; o <<= 1) {
        int x = (tid >= o) ? sc[tid - o] : 0;
        __syncthreads();
        sc[tid] += x;
        __syncthreads();
    }
    if (tid < NBUCK) {
        int h = hist[tid];
        bstart[tid] = sc[tid] - h;                   // exclusive LDS start
        gb[tid] = h ? atomicAdd(&gcur[tid], h) : 0;  // reserve run in fixed region
    }
    __syncthreads();
    int tot = sc[NBUCK - 1];                         // items in this block

    // place items into LDS at bucket-sorted slots (record bucket id per slot)
    for (int j = 0; j < KB_ITEMS; ++j) {
        int r = rr[j];
        if (r >= 0) {
            long i = base + j * KB_BLOCK + tid;
            int c; float v;
            if (i < NNZ_FEAT) { c = fcols[i]; v = fvals[i]; }
            else              { c = acols[i - NNZ_FEAT]; v = avals[i - NNZ_FEAT]; }
            int b = r >> 9;
            int slot = bstart[b] + atomicAdd(&lcnt[b], 1);
            s_pk[slot] = ((r & 511) << PK_COL_BITS) | c;
            s_vl[slot] = v;
            s_bid[slot] = (unsigned short)b;
        }
    }
    __syncthreads();

    // item-parallel flush: consecutive slots -> consecutive global addresses
    for (int s = tid; s < tot; s += KB_BLOCK) {
        int b = s_bid[s];
        int dest = gb[b] + (s - bstart[b]);
        tmp_pk[dest] = s_pk[s];
        tmp_vl[dest] = s_vl[s];
    }
}

// ---------------- scan bucket counts -> dense CSR bucket starts ----------------

__global__ void k_scand(const int* __restrict__ gcur, int* __restrict__ dstart) {
    __shared__ int s[512];
    int t = threadIdx.x;
    int cnt = (t < NBUCK) ? (gcur[t] - t * BCAP) : 0;
    s[t] = cnt;
    __syncthreads();
    for (int o = 1; o < 512; o <<= 1) {
        int x = (t >= o) ? s[t - o] : 0;
        __syncthreads();
        s[t] += x;
        __syncthreads();
    }
    if (t < NBUCK) dstart[t] = s[t] - cnt;           // exclusive
}

// ---------------- stage C (fused): count rows, in-bucket scan -> S, place ------
// 512 threads: one bucket-row per thread; loops stride 512.

__global__ __launch_bounds__(512) void kC(const int* __restrict__ gcur,
                                          const int* __restrict__ dstart,
                                          const int* __restrict__ tmp_pk,
                                          const float* __restrict__ tmp_vl,
                                          int2* __restrict__ pairs,
                                          int* __restrict__ S) {
    __shared__ int rcnt[BROWS];
    __shared__ int sc2[BROWS];
    __shared__ int rcur[BROWS];
    int tid = threadIdx.x;
    int b = blockIdx.x, rbase = b << 9;
    rcnt[tid] = 0;
    __syncthreads();
    int e0 = b * BCAP;
    int e1 = e0 + (gcur[b] - b * BCAP);
    int dbase = dstart[b];
    for (int i = e0 + tid; i < e1; i += 512)
        atomicAdd(&rcnt[tmp_pk[i] >> PK_COL_BITS], 1);
    __syncthreads();
    // inclusive scan of 512 row counts, one element per thread
    sc2[tid] = rcnt[tid];
    __syncthreads();
    for (int o = 1; o < 512; o <<= 1) {
        int x = (tid >= o) ? sc2[tid - o] : 0;
        __syncthreads();
        sc2[tid] += x;
        __syncthreads();
    }
    int ex0 = dbase + sc2[tid] - rcnt[tid];
    S[rbase + tid] = ex0;
    rcur[tid] = ex0;
    __syncthreads();
    for (int i = e0 + tid; i < e1; i += 512) {
        int pk = tmp_pk[i];
        float v = tmp_vl[i];
        int p = atomicAdd(&rcur[pk >> PK_COL_BITS], 1);
        pairs[p] = make_int2(pk & PK_COL_MASK, __float_as_int(v));
    }
}

// ---------------- W fp32 -> fp16 ----------------

__global__ __launch_bounds__(256) void k_wconv(const float* __restrict__ W,
                                               __half2* __restrict__ Wh) {
    int i = blockIdx.x * 256 + threadIdx.x;
    if (i < IN_CH * OUT_CH / 2) {
        float2 f = ((const float2*)W)[i];
        Wh[i] = __floats2half2_rn(f.x, f.y);
    }
}

// ---------------- SpMM kernels ----------------
// wave per row; lane l preloads pairs[k0+l] for a 64-chunk; (col,val) broadcast
// via readlane -> gathers are SGPR-base loads with no inter-load dependency.
// 8-deep groups (R10 sweet spot). Each lane: 2 channels packed in __half2.

#define SPMM_GROUP(OFS)                                                        \
    _Pragma("unroll")                                                          \
    for (int j = 0; j < 8; ++j) {                                              \
        int c = __builtin_amdgcn_readlane(pp.x, (OFS) + j);                    \
        float v = __int_as_float(__builtin_amdgcn_readlane(pp.y, (OFS) + j));  \
        float2 f = __half22float2(HSRC_AT(c));                                 \
        if (j & 1) { a1.x = fmaf(v, f.x, a1.x); a1.y = fmaf(v, f.y, a1.y); }   \
        else       { a0.x = fmaf(v, f.x, a0.x); a0.y = fmaf(v, f.y, a0.y); }   \
    }

#define SPMM_BODY(ACC_INIT)                                                    \
    int row = blockIdx.x * 4 + (threadIdx.x >> 6);                             \
    int lane = threadIdx.x & 63;                                               \
    int k0 = __builtin_amdgcn_readfirstlane(SROW0);                            \
    int k1 = __builtin_amdgcn_readfirstlane(SROW1);                            \
    float2 a0 = ACC_INIT;                                                      \
    float2 a1 = make_float2(0.0f, 0.0f);                                       \
    for (int base = k0; base < k1; base += 64) {                               \
        int idx = base + lane;                                                 \
        int2 pp = (idx < k1) ? pairs[idx] : make_int2(0, 0);                   \
        int n = k1 - base; if (n > 64) n = 64;                                 \
        int full = n & ~7;                                                     \
        for (int jj = 0; jj < full; jj += 8) { SPMM_GROUP(jj) }                \
        if (full < n) { SPMM_GROUP(full) }                                     \
    }

// h0 = relu(F*Wh + b), output fp16
__global__ __launch_bounds__(256) void spmm_w(const int* __restrict__ S,
                                              const int2* __restrict__ pairs,
                                              const __half2* __restrict__ Wh,
                                              const float* __restrict__ bias,
                                              __half2* __restrict__ out16) {
#define SROW0 S[row]
#define SROW1 S[row + 1]
#define HSRC_AT(c) Wh[(size_t)(c) * (OUT_CH / 2) + lane]
    SPMM_BODY(((const float2*)bias)[lane])
#undef HSRC_AT
#undef SROW0
#undef SROW1
    float rx = fmaxf(a0.x + a1.x, 0.0f);
    float ry = fmaxf(a0.y + a1.y, 0.0f);
    out16[(size_t)row * (OUT_CH / 2) + lane] = __floats2half2_rn(rx, ry);
}

// h = A*h, fp16 in -> fp16 out
__global__ __launch_bounds__(256) void spmm_adj_hh(const int* __restrict__ S,
                                                   const int2* __restrict__ pairs,
                                                   const __half2* __restrict__ hin,
                                                   __half2* __restrict__ hout) {
#define SROW0 S[N_NODES + row]
#define SROW1 S[N_NODES + row + 1]
#define HSRC_AT(c) hin[(size_t)(c) * (OUT_CH / 2) + lane]
    SPMM_BODY(make_float2(0.0f, 0.0f))
#undef HSRC_AT
#undef SROW0
#undef SROW1
    hout[(size_t)row * (OUT_CH / 2) + lane] = __floats2half2_rn(a0.x + a1.x, a0.y + a1.y);
}

// final hop: fp16 in -> fp32 out (d_out)
__global__ __launch_bounds__(256) void spmm_adj_hf(const int* __restrict__ S,
                                                   const int2* __restrict__ pairs,
                                                   const __half2* __restrict__ hin,
                                                   float* __restrict__ out) {
#define SROW0 S[N_NODES + row]
#define SROW1 S[N_NODES + row + 1]
#define HSRC_AT(c) hin[(size_t)(c) * (OUT_CH / 2) + lane]
    SPMM_BODY(make_float2(0.0f, 0.0f))
#undef HSRC_AT
#undef SROW0
#undef SROW1
    float2 acc;
    acc.x = a0.x + a1.x;
    acc.y = a0.y + a1.y;
    ((float2*)(out + (size_t)row * OUT_CH))[lane] = acc;
}

// ---------------- driver ----------------

extern "C" void kernel_launch(void* const* d_in, const int* in_sizes, int n_in,
                              void* d_out, int out_size, void* d_ws, size_t ws_size,
                              hipStream_t stream) {
    const int*   frows = (const int*)d_in[0];
    const int*   fcols = (const int*)d_in[1];
    const float* fvals = (const float*)d_in[2];
    const int*   arows = (const int*)d_in[3];
    const int*   acols = (const int*)d_in[4];
    const float* avals = (const float*)d_in[5];
    const float* W     = (const float*)d_in[6];
    const float* bias  = (const float*)d_in[7];
    float* out = (float*)d_out;

    char* ws = (char*)d_ws;
    size_t off = 0;
    auto alloc = [&](size_t bytes) {
        size_t o = off;
        off = (off + bytes + 255) & ~(size_t)255;
        return o;
    };
    int*  S      = (int*) (ws + alloc((size_t)NROWP * 4));
    int*  gcur   = (int*) (ws + alloc(512 * 4));
    int*  dstart = (int*) (ws + alloc(512 * 4));
    int2* pairs  = (int2*)(ws + alloc((size_t)NNZ_TOT * 8));
    __half2* Wh  = (__half2*)(ws + alloc((size_t)IN_CH * OUT_CH * 2));
    char* hraw   = ws + alloc(2 * (size_t)N_NODES * OUT_CH * 2);   // two fp16 h buffers
    __half2* hA  = (__half2*)hraw;
    __half2* hB  = (__half2*)(hraw + (size_t)N_NODES * OUT_CH * 2);
    // tmp buffers alias onto hA/hB region (51.2 MB): dead before spmm_w runs
    int*   tmp_pk = (int*)hraw;                                          // 19.2 MB
    float* tmp_vl = (float*)(hraw + (((size_t)NBUCK * BCAP * 4 + 255) & ~(size_t)255)); // 19.2 MB
    (void)ws_size; (void)off; (void)in_sizes; (void)n_in; (void)out_size;

    k_init<<<1, 512, 0, stream>>>(gcur);
    k_wconv<<<(IN_CH * OUT_CH / 2 + 255) / 256, 256, 0, stream>>>(W, Wh);
    kB<<<KB_GRID, KB_BLOCK, 0, stream>>>(frows, fcols, fvals, arows, acols, avals,
                                         gcur, tmp_pk, tmp_vl);
    k_scand<<<1, 512, 0, stream>>>(gcur, dstart);
    kC<<<NBUCK, 512, 0, stream>>>(gcur, dstart, tmp_pk, tmp_vl, pairs, S);

    spmm_w<<<N_NODES / 4, 256, 0, stream>>>(S, pairs, Wh, bias, hA);

    spmm_adj_hh<<<N_NODES / 4, 256, 0, stream>>>(S, pairs, hA, hB);
    spmm_adj_hh<<<N_NODES / 4, 256, 0, stream>>>(S, pairs, hB, hA);
    spmm_adj_hf<<<N_NODES / 4, 256, 0, stream>>>(S, pairs, hA, out);
}

// Round 14
// 289.818 us; speedup vs baseline: 1.2129x; 1.0176x over previous
//
#include <hip/hip_runtime.h>
#include <hip/hip_fp16.h>

#define N_NODES 100000
#define IN_CH 2048
#define OUT_CH 128
#define NNZ_FEAT 2000000
#define NNZ_ADJ 1600000
#define NNZ_TOT (NNZ_FEAT + NNZ_ADJ)
#define BROWS 512                      // rows per bucket
#define NBUCK 391                      // ceil(200000 / 512)
#define NROWP (NBUCK * BROWS)          // 200192 padded row-count length
#define BCAP 12288                     // fixed tmp slots per bucket (>20 sigma)
#define KC_MAX 24                      // BCAP / 512 items per kC thread
#define KB_BLOCK 512
#define KB_ITEMS 8
#define KB_CHUNK (KB_BLOCK * KB_ITEMS) // 4096
#define KB_GRID ((NNZ_TOT + KB_CHUNK - 1) / KB_CHUNK)  // 879
#define SPMM_GRID 4096                 // persistent grid-stride blocks

// pack: (row_in_bucket << 17) | col     (col < 131072, rib < 512)
#define PK_COL_BITS 17
#define PK_COL_MASK ((1 << PK_COL_BITS) - 1)

// ---------------- init: gcur[b] = b * BCAP ----------------

__global__ void k_init(int* __restrict__ gcur) {
    int t = threadIdx.x;
    if (t < NBUCK) gcur[t] = t * BCAP;
}

// ---------------- stage B: LDS bucket-sort then item-parallel coalesced flush ----

__global__ __launch_bounds__(KB_BLOCK) void kB(const int* __restrict__ frows,
                                               const int* __restrict__ fcols,
                                               const float* __restrict__ fvals,
                                               const int* __restrict__ arows,
                                               const int* __restrict__ acols,
                                               const float* __restrict__ avals,
                                               int* __restrict__ gcur,
                                               int2* __restrict__ tmp) {
    __shared__ int hist[NBUCK];
    __shared__ int lcnt[NBUCK];
    __shared__ int gb[NBUCK];
    __shared__ int bstart[NBUCK];
    __shared__ int sc[512];
    __shared__ int s_pk[KB_CHUNK];
    __shared__ float s_vl[KB_CHUNK];
    __shared__ unsigned short s_bid[KB_CHUNK];

    int tid = threadIdx.x;
    if (tid < NBUCK) { hist[tid] = 0; lcnt[tid] = 0; }
    __syncthreads();

    long base = (long)blockIdx.x * KB_CHUNK;
    int rr[KB_ITEMS];
    for (int j = 0; j < KB_ITEMS; ++j) {
        long i = base + j * KB_BLOCK + tid;
        int r = -1;
        if (i < NNZ_TOT) {
            r = (i < NNZ_FEAT) ? frows[i] : (N_NODES + arows[i - NNZ_FEAT]);
            atomicAdd(&hist[r >> 9], 1);
        }
        rr[j] = r;
    }
    __syncthreads();

    // inclusive scan of hist (padded to 512), one element per thread
    sc[tid] = (tid < NBUCK) ? hist[tid] : 0;
    __syncthreads();
    for (int o = 1; o < 512; o <<= 1) {
        int x = (tid >= o) ? sc[tid - o] : 0;
        __syncthreads();
        sc[tid] += x;
        __syncthreads();
    }
    if (tid < NBUCK) {
        int h = hist[tid];
        bstart[tid] = sc[tid] - h;                   // exclusive LDS start
        gb[tid] = h ? atomicAdd(&gcur[tid], h) : 0;  // reserve run in fixed region
    }
    __syncthreads();
    int tot = sc[NBUCK - 1];                         // items in this block

    // place items into LDS at bucket-sorted slots (record bucket id per slot)
    for (int j = 0; j < KB_ITEMS; ++j) {
        int r = rr[j];
        if (r >= 0) {
            long i = base + j * KB_BLOCK + tid;
            int c; float v;
            if (i < NNZ_FEAT) { c = fcols[i]; v = fvals[i]; }
            else              { c = acols[i - NNZ_FEAT]; v = avals[i - NNZ_FEAT]; }
            int b = r >> 9;
            int slot = bstart[b] + atomicAdd(&lcnt[b], 1);
            s_pk[slot] = ((r & 511) << PK_COL_BITS) | c;
            s_vl[slot] = v;
            s_bid[slot] = (unsigned short)b;
        }
    }
    __syncthreads();

    // item-parallel flush: consecutive slots -> consecutive global addresses
    for (int s = tid; s < tot; s += KB_BLOCK) {
        int b = s_bid[s];
        int dest = gb[b] + (s - bstart[b]);
        tmp[dest] = make_int2(s_pk[s], __float_as_int(s_vl[s]));
    }
}

// ---------------- scan bucket counts -> dense CSR bucket starts ----------------

__global__ void k_scand(const int* __restrict__ gcur, int* __restrict__ dstart) {
    __shared__ int s[512];
    int t = threadIdx.x;
    int cnt = (t < NBUCK) ? (gcur[t] - t * BCAP) : 0;
    s[t] = cnt;
    __syncthreads();
    for (int o = 1; o < 512; o <<= 1) {
        int x = (t >= o) ? s[t - o] : 0;
        __syncthreads();
        s[t] += x;
        __syncthreads();
    }
    if (t < NBUCK) dstart[t] = s[t] - cnt;           // exclusive
}

// ---------------- stage C (single-pass): items -> regs, count, scan, place -----

__global__ __launch_bounds__(512) void kC(const int* __restrict__ gcur,
                                          const int* __restrict__ dstart,
                                          const int2* __restrict__ tmp,
                                          int2* __restrict__ pairs,
                                          int* __restrict__ S) {
    __shared__ int rcnt[BROWS];
    __shared__ int sc2[BROWS];
    __shared__ int rcur[BROWS];
    int tid = threadIdx.x;
    int b = blockIdx.x, rbase = b << 9;
    rcnt[tid] = 0;
    __syncthreads();
    int e0 = b * BCAP;
    int cnt = gcur[b] - e0;
    int dbase = dstart[b];

    // load my items once (static indexing -> registers)
    int2 it[KC_MAX];
#pragma unroll
    for (int i = 0; i < KC_MAX; ++i) {
        int idx = i * 512 + tid;
        if (idx < cnt) it[i] = tmp[e0 + idx];
    }
    // count
#pragma unroll
    for (int i = 0; i < KC_MAX; ++i) {
        if (i * 512 + tid < cnt) atomicAdd(&rcnt[it[i].x >> PK_COL_BITS], 1);
    }
    __syncthreads();
    // inclusive scan of 512 row counts
    sc2[tid] = rcnt[tid];
    __syncthreads();
    for (int o = 1; o < 512; o <<= 1) {
        int x = (tid >= o) ? sc2[tid - o] : 0;
        __syncthreads();
        sc2[tid] += x;
        __syncthreads();
    }
    int ex0 = dbase + sc2[tid] - rcnt[tid];
    S[rbase + tid] = ex0;
    rcur[tid] = ex0;
    __syncthreads();
    // place from registers
#pragma unroll
    for (int i = 0; i < KC_MAX; ++i) {
        if (i * 512 + tid < cnt) {
            int p = atomicAdd(&rcur[it[i].x >> PK_COL_BITS], 1);
            pairs[p] = make_int2(it[i].x & PK_COL_MASK, it[i].y);
        }
    }
}

// ---------------- W fp32 -> fp16 ----------------

__global__ __launch_bounds__(256) void k_wconv(const float* __restrict__ W,
                                               __half2* __restrict__ Wh) {
    int i = blockIdx.x * 256 + threadIdx.x;
    if (i < IN_CH * OUT_CH / 2) {
        float2 f = ((const float2*)W)[i];
        Wh[i] = __floats2half2_rn(f.x, f.y);
    }
}

// ---------------- SpMM kernels (grid-stride, wave per row) ----------------
// lane l preloads pairs[k0+l] for a 64-chunk; (col,val) broadcast via readlane;
// 8-deep gather groups; 2 channels per lane in __half2.

#define SPMM_GROUP(OFS)                                                        \
    _Pragma("unroll")                                                          \
    for (int j = 0; j < 8; ++j) {                                              \
        int c = __builtin_amdgcn_readlane(pp.x, (OFS) + j);                    \
        float v = __int_as_float(__builtin_amdgcn_readlane(pp.y, (OFS) + j));  \
        float2 f = __half22float2(HSRC_AT(c));                                 \
        if (j & 1) { a1.x = fmaf(v, f.x, a1.x); a1.y = fmaf(v, f.y, a1.y); }   \
        else       { a0.x = fmaf(v, f.x, a0.x); a0.y = fmaf(v, f.y, a0.y); }   \
    }

#define SPMM_ROW(SOFS, ACC_INIT)                                               \
    int row = rg * 4 + wid;                                                    \
    int k0 = __builtin_amdgcn_readfirstlane(S[(SOFS) + row]);                  \
    int k1 = __builtin_amdgcn_readfirstlane(S[(SOFS) + row + 1]);              \
    float2 a0 = ACC_INIT;                                                      \
    float2 a1 = make_float2(0.0f, 0.0f);                                       \
    for (int base = k0; base < k1; base += 64) {                               \
        int idx = base + lane;                                                 \
        int2 pp = (idx < k1) ? pairs[idx] : make_int2(0, 0);                   \
        int n = k1 - base; if (n > 64) n = 64;                                 \
        int full = n & ~7;                                                     \
        for (int jj = 0; jj < full; jj += 8) { SPMM_GROUP(jj) }                \
        if (full < n) { SPMM_GROUP(full) }                                     \
    }

// h0 = relu(F*Wh + b), output fp16
__global__ __launch_bounds__(256) void spmm_w(const int* __restrict__ S,
                                              const int2* __restrict__ pairs,
                                              const __half2* __restrict__ Wh,
                                              const float* __restrict__ bias,
                                              __half2* __restrict__ out16) {
    int wid = threadIdx.x >> 6, lane = threadIdx.x & 63;
    float2 binit = ((const float2*)bias)[lane];
    for (int rg = blockIdx.x; rg < N_NODES / 4; rg += SPMM_GRID) {
#define HSRC_AT(c) Wh[(size_t)(c) * (OUT_CH / 2) + lane]
        SPMM_ROW(0, binit)
#undef HSRC_AT
        float rx = fmaxf(a0.x + a1.x, 0.0f);
        float ry = fmaxf(a0.y + a1.y, 0.0f);
        out16[(size_t)row * (OUT_CH / 2) + lane] = __floats2half2_rn(rx, ry);
    }
}

// h = A*h, fp16 in -> fp16 out
__global__ __launch_bounds__(256) void spmm_adj_hh(const int* __restrict__ S,
                                                   const int2* __restrict__ pairs,
                                                   const __half2* __restrict__ hin,
                                                   __half2* __restrict__ hout) {
    int wid = threadIdx.x >> 6, lane = threadIdx.x & 63;
    for (int rg = blockIdx.x; rg < N_NODES / 4; rg += SPMM_GRID) {
#define HSRC_AT(c) hin[(size_t)(c) * (OUT_CH / 2) + lane]
        SPMM_ROW(N_NODES, make_float2(0.0f, 0.0f))
#undef HSRC_AT
        hout[(size_t)row * (OUT_CH / 2) + lane] = __floats2half2_rn(a0.x + a1.x, a0.y + a1.y);
    }
}

// final hop: fp16 in -> fp32 out (d_out)
__global__ __launch_bounds__(256) void spmm_adj_hf(const int* __restrict__ S,
                                                   const int2* __restrict__ pairs,
                                                   const __half2* __restrict__ hin,
                                                   float* __restrict__ out) {
    int wid = threadIdx.x >> 6, lane = threadIdx.x & 63;
    for (int rg = blockIdx.x; rg < N_NODES / 4; rg += SPMM_GRID) {
#define HSRC_AT(c) hin[(size_t)(c) * (OUT_CH / 2) + lane]
        SPMM_ROW(N_NODES, make_float2(0.0f, 0.0f))
#undef HSRC_AT
        float2 acc;
        acc.x = a0.x + a1.x;
        acc.y = a0.y + a1.y;
        ((float2*)(out + (size_t)row * OUT_CH))[lane] = acc;
    }
}

// ---------------- driver ----------------

extern "C" void kernel_launch(void* const* d_in, const int* in_sizes, int n_in,
                              void* d_out, int out_size, void* d_ws, size_t ws_size,
                              hipStream_t stream) {
    const int*   frows = (const int*)d_in[0];
    const int*   fcols = (const int*)d_in[1];
    const float* fvals = (const float*)d_in[2];
    const int*   arows = (const int*)d_in[3];
    const int*   acols = (const int*)d_in[4];
    const float* avals = (const float*)d_in[5];
    const float* W     = (const float*)d_in[6];
    const float* bias  = (const float*)d_in[7];
    float* out = (float*)d_out;

    char* ws = (char*)d_ws;
    size_t off = 0;
    auto alloc = [&](size_t bytes) {
        size_t o = off;
        off = (off + bytes + 255) & ~(size_t)255;
        return o;
    };
    int*  S      = (int*) (ws + alloc((size_t)NROWP * 4));
    int*  gcur   = (int*) (ws + alloc(512 * 4));
    int*  dstart = (int*) (ws + alloc(512 * 4));
    int2* pairs  = (int2*)(ws + alloc((size_t)NNZ_TOT * 8));
    __half2* Wh  = (__half2*)(ws + alloc((size_t)IN_CH * OUT_CH * 2));
    char* hraw   = ws + alloc(2 * (size_t)N_NODES * OUT_CH * 2);   // two fp16 h buffers
    __half2* hA  = (__half2*)hraw;
    __half2* hB  = (__half2*)(hraw + (size_t)N_NODES * OUT_CH * 2);
    // tmp (38.4 MB int2) aliases onto hA/hB region (51.2 MB): dead before spmm_w
    int2* tmp = (int2*)hraw;
    (void)ws_size; (void)off; (void)in_sizes; (void)n_in; (void)out_size;

    k_init<<<1, 512, 0, stream>>>(gcur);
    k_wconv<<<(IN_CH * OUT_CH / 2 + 255) / 256, 256, 0, stream>>>(W, Wh);
    kB<<<KB_GRID, KB_BLOCK, 0, stream>>>(frows, fcols, fvals, arows, acols, avals,
                                         gcur, tmp);
    k_scand<<<1, 512, 0, stream>>>(gcur, dstart);
    kC<<<NBUCK, 512, 0, stream>>>(gcur, dstart, tmp, pairs, S);

    spmm_w<<<SPMM_GRID, 256, 0, stream>>>(S, pairs, Wh, bias, hA);

    spmm_adj_hh<<<SPMM_GRID, 256, 0, stream>>>(S, pairs, hA, hB);
    spmm_adj_hh<<<SPMM_GRID, 256, 0, stream>>>(S, pairs, hB, hA);
    spmm_adj_hf<<<SPMM_GRID, 256, 0, stream>>>(S, pairs, hA, out);
}

// Round 15
// 281.239 us; speedup vs baseline: 1.2499x; 1.0305x over previous
//
#include <hip/hip_runtime.h>
#include <hip/hip_fp16.h>

#define N_NODES 100000
#define IN_CH 2048
#define OUT_CH 128
#define NNZ_FEAT 2000000
#define NNZ_ADJ 1600000
#define NNZ_TOT (NNZ_FEAT + NNZ_ADJ)
#define BROWS 512                      // rows per bucket
#define NBUCK 391                      // ceil(200000 / 512)
#define NROWP (NBUCK * BROWS)          // 200192 padded row-count length
#define BCAP 12288                     // fixed tmp slots per bucket (>20 sigma)
#define KC_MAX 24                      // BCAP / 512 items per kC thread
#define KB_BLOCK 512
#define KB_ITEMS 8
#define KB_CHUNK (KB_BLOCK * KB_ITEMS) // 4096
#define KB_GRID ((NNZ_TOT + KB_CHUNK - 1) / KB_CHUNK)  // 879

// pack: (row_in_bucket << 17) | col     (col < 131072, rib < 512)
#define PK_COL_BITS 17
#define PK_COL_MASK ((1 << PK_COL_BITS) - 1)

// ---------------- init: gcur[b] = b * BCAP ----------------

__global__ void k_init(int* __restrict__ gcur) {
    int t = threadIdx.x;
    if (t < NBUCK) gcur[t] = t * BCAP;
}

// ---------------- stage B: LDS bucket-sort then item-parallel coalesced flush ----

__global__ __launch_bounds__(KB_BLOCK) void kB(const int* __restrict__ frows,
                                               const int* __restrict__ fcols,
                                               const float* __restrict__ fvals,
                                               const int* __restrict__ arows,
                                               const int* __restrict__ acols,
                                               const float* __restrict__ avals,
                                               int* __restrict__ gcur,
                                               int2* __restrict__ tmp) {
    __shared__ int hist[NBUCK];
    __shared__ int lcnt[NBUCK];
    __shared__ int gb[NBUCK];
    __shared__ int bstart[NBUCK];
    __shared__ int sc[512];
    __shared__ int s_pk[KB_CHUNK];
    __shared__ float s_vl[KB_CHUNK];
    __shared__ unsigned short s_bid[KB_CHUNK];

    int tid = threadIdx.x;
    if (tid < NBUCK) { hist[tid] = 0; lcnt[tid] = 0; }
    __syncthreads();

    long base = (long)blockIdx.x * KB_CHUNK;
    int rr[KB_ITEMS];
    for (int j = 0; j < KB_ITEMS; ++j) {
        long i = base + j * KB_BLOCK + tid;
        int r = -1;
        if (i < NNZ_TOT) {
            r = (i < NNZ_FEAT) ? frows[i] : (N_NODES + arows[i - NNZ_FEAT]);
            atomicAdd(&hist[r >> 9], 1);
        }
        rr[j] = r;
    }
    __syncthreads();

    // inclusive scan of hist (padded to 512), one element per thread
    sc[tid] = (tid < NBUCK) ? hist[tid] : 0;
    __syncthreads();
    for (int o = 1; o < 512; o <<= 1) {
        int x = (tid >= o) ? sc[tid - o] : 0;
        __syncthreads();
        sc[tid] += x;
        __syncthreads();
    }
    if (tid < NBUCK) {
        int h = hist[tid];
        bstart[tid] = sc[tid] - h;                   // exclusive LDS start
        gb[tid] = h ? atomicAdd(&gcur[tid], h) : 0;  // reserve run in fixed region
    }
    __syncthreads();
    int tot = sc[NBUCK - 1];                         // items in this block

    // place items into LDS at bucket-sorted slots (record bucket id per slot)
    for (int j = 0; j < KB_ITEMS; ++j) {
        int r = rr[j];
        if (r >= 0) {
            long i = base + j * KB_BLOCK + tid;
            int c; float v;
            if (i < NNZ_FEAT) { c = fcols[i]; v = fvals[i]; }
            else              { c = acols[i - NNZ_FEAT]; v = avals[i - NNZ_FEAT]; }
            int b = r >> 9;
            int slot = bstart[b] + atomicAdd(&lcnt[b], 1);
            s_pk[slot] = ((r & 511) << PK_COL_BITS) | c;
            s_vl[slot] = v;
            s_bid[slot] = (unsigned short)b;
        }
    }
    __syncthreads();

    // item-parallel flush: consecutive slots -> consecutive global addresses
    for (int s = tid; s < tot; s += KB_BLOCK) {
        int b = s_bid[s];
        int dest = gb[b] + (s - bstart[b]);
        tmp[dest] = make_int2(s_pk[s], __float_as_int(s_vl[s]));
    }
}

// ---------------- scan bucket counts -> dense CSR bucket starts ----------------

__global__ void k_scand(const int* __restrict__ gcur, int* __restrict__ dstart) {
    __shared__ int s[512];
    int t = threadIdx.x;
    int cnt = (t < NBUCK) ? (gcur[t] - t * BCAP) : 0;
    s[t] = cnt;
    __syncthreads();
    for (int o = 1; o < 512; o <<= 1) {
        int x = (t >= o) ? s[t - o] : 0;
        __syncthreads();
        s[t] += x;
        __syncthreads();
    }
    if (t < NBUCK) dstart[t] = s[t] - cnt;           // exclusive
}

// ---------------- stage C (single-pass): items -> regs, count, scan, place -----

__global__ __launch_bounds__(512) void kC(const int* __restrict__ gcur,
                                          const int* __restrict__ dstart,
                                          const int2* __restrict__ tmp,
                                          int2* __restrict__ pairs,
                                          int* __restrict__ S) {
    __shared__ int rcnt[BROWS];
    __shared__ int sc2[BROWS];
    __shared__ int rcur[BROWS];
    int tid = threadIdx.x;
    int b = blockIdx.x, rbase = b << 9;
    rcnt[tid] = 0;
    __syncthreads();
    int e0 = b * BCAP;
    int cnt = gcur[b] - e0;
    int dbase = dstart[b];

    // load my items once (static indexing -> registers)
    int2 it[KC_MAX];
#pragma unroll
    for (int i = 0; i < KC_MAX; ++i) {
        int idx = i * 512 + tid;
        if (idx < cnt) it[i] = tmp[e0 + idx];
    }
    // count
#pragma unroll
    for (int i = 0; i < KC_MAX; ++i) {
        if (i * 512 + tid < cnt) atomicAdd(&rcnt[it[i].x >> PK_COL_BITS], 1);
    }
    __syncthreads();
    // inclusive scan of 512 row counts
    sc2[tid] = rcnt[tid];
    __syncthreads();
    for (int o = 1; o < 512; o <<= 1) {
        int x = (tid >= o) ? sc2[tid - o] : 0;
        __syncthreads();
        sc2[tid] += x;
        __syncthreads();
    }
    int ex0 = dbase + sc2[tid] - rcnt[tid];
    S[rbase + tid] = ex0;
    rcur[tid] = ex0;
    __syncthreads();
    // place from registers
#pragma unroll
    for (int i = 0; i < KC_MAX; ++i) {
        if (i * 512 + tid < cnt) {
            int p = atomicAdd(&rcur[it[i].x >> PK_COL_BITS], 1);
            pairs[p] = make_int2(it[i].x & PK_COL_MASK, it[i].y);
        }
    }
}

// ---------------- W fp32 -> fp16 ----------------

__global__ __launch_bounds__(256) void k_wconv(const float* __restrict__ W,
                                               __half2* __restrict__ Wh) {
    int i = blockIdx.x * 256 + threadIdx.x;
    if (i < IN_CH * OUT_CH / 2) {
        float2 f = ((const float2*)W)[i];
        Wh[i] = __floats2half2_rn(f.x, f.y);
    }
}

// ---------------- SpMM kernels (exact grid, wave per row) ----------------
// lane l preloads pairs[k0+l] for a 64-chunk; (col,val) broadcast via readlane;
// 8-deep gather groups; 2 channels per lane in __half2.

#define SPMM_GROUP(OFS)                                                        \
    _Pragma("unroll")                                                          \
    for (int j = 0; j < 8; ++j) {                                              \
        int c = __builtin_amdgcn_readlane(pp.x, (OFS) + j);                    \
        float v = __int_as_float(__builtin_amdgcn_readlane(pp.y, (OFS) + j));  \
        float2 f = __half22float2(HSRC_AT(c));                                 \
        if (j & 1) { a1.x = fmaf(v, f.x, a1.x); a1.y = fmaf(v, f.y, a1.y); }   \
        else       { a0.x = fmaf(v, f.x, a0.x); a0.y = fmaf(v, f.y, a0.y); }   \
    }

#define SPMM_BODY(SOFS, ACC_INIT)                                              \
    int row = blockIdx.x * 4 + (threadIdx.x >> 6);                             \
    int lane = threadIdx.x & 63;                                               \
    int k0 = __builtin_amdgcn_readfirstlane(S[(SOFS) + row]);                  \
    int k1 = __builtin_amdgcn_readfirstlane(S[(SOFS) + row + 1]);              \
    float2 a0 = ACC_INIT;                                                      \
    float2 a1 = make_float2(0.0f, 0.0f);                                       \
    for (int base = k0; base < k1; base += 64) {                               \
        int idx = base + lane;                                                 \
        int2 pp = (idx < k1) ? pairs[idx] : make_int2(0, 0);                   \
        int n = k1 - base; if (n > 64) n = 64;                                 \
        int full = n & ~7;                                                     \
        for (int jj = 0; jj < full; jj += 8) { SPMM_GROUP(jj) }                \
        if (full < n) { SPMM_GROUP(full) }                                     \
    }

// h0 = relu(F*Wh + b), output fp16
__global__ __launch_bounds__(256) void spmm_w(const int* __restrict__ S,
                                              const int2* __restrict__ pairs,
                                              const __half2* __restrict__ Wh,
                                              const float* __restrict__ bias,
                                              __half2* __restrict__ out16) {
#define HSRC_AT(c) Wh[(size_t)(c) * (OUT_CH / 2) + lane]
    SPMM_BODY(0, ((const float2*)bias)[lane])
#undef HSRC_AT
    float rx = fmaxf(a0.x + a1.x, 0.0f);
    float ry = fmaxf(a0.y + a1.y, 0.0f);
    out16[(size_t)row * (OUT_CH / 2) + lane] = __floats2half2_rn(rx, ry);
}

// h = A*h, fp16 in -> fp16 out
__global__ __launch_bounds__(256) void spmm_adj_hh(const int* __restrict__ S,
                                                   const int2* __restrict__ pairs,
                                                   const __half2* __restrict__ hin,
                                                   __half2* __restrict__ hout) {
#define HSRC_AT(c) hin[(size_t)(c) * (OUT_CH / 2) + lane]
    SPMM_BODY(N_NODES, make_float2(0.0f, 0.0f))
#undef HSRC_AT
    hout[(size_t)row * (OUT_CH / 2) + lane] = __floats2half2_rn(a0.x + a1.x, a0.y + a1.y);
}

// final hop: fp16 in -> fp32 out (d_out)
__global__ __launch_bounds__(256) void spmm_adj_hf(const int* __restrict__ S,
                                                   const int2* __restrict__ pairs,
                                                   const __half2* __restrict__ hin,
                                                   float* __restrict__ out) {
#define HSRC_AT(c) hin[(size_t)(c) * (OUT_CH / 2) + lane]
    SPMM_BODY(N_NODES, make_float2(0.0f, 0.0f))
#undef HSRC_AT
    float2 acc;
    acc.x = a0.x + a1.x;
    acc.y = a0.y + a1.y;
    ((float2*)(out + (size_t)row * OUT_CH))[lane] = acc;
}

// ---------------- driver ----------------

extern "C" void kernel_launch(void* const* d_in, const int* in_sizes, int n_in,
                              void* d_out, int out_size, void* d_ws, size_t ws_size,
                              hipStream_t stream) {
    const int*   frows = (const int*)d_in[0];
    const int*   fcols = (const int*)d_in[1];
    const float* fvals = (const float*)d_in[2];
    const int*   arows = (const int*)d_in[3];
    const int*   acols = (const int*)d_in[4];
    const float* avals = (const float*)d_in[5];
    const float* W     = (const float*)d_in[6];
    const float* bias  = (const float*)d_in[7];
    float* out = (float*)d_out;

    char* ws = (char*)d_ws;
    size_t off = 0;
    auto alloc = [&](size_t bytes) {
        size_t o = off;
        off = (off + bytes + 255) & ~(size_t)255;
        return o;
    };
    int*  S      = (int*) (ws + alloc((size_t)NROWP * 4));
    int*  gcur   = (int*) (ws + alloc(512 * 4));
    int*  dstart = (int*) (ws + alloc(512 * 4));
    int2* pairs  = (int2*)(ws + alloc((size_t)NNZ_TOT * 8));
    __half2* Wh  = (__half2*)(ws + alloc((size_t)IN_CH * OUT_CH * 2));
    char* hraw   = ws + alloc(2 * (size_t)N_NODES * OUT_CH * 2);   // two fp16 h buffers
    __half2* hA  = (__half2*)hraw;
    __half2* hB  = (__half2*)(hraw + (size_t)N_NODES * OUT_CH * 2);
    // tmp (38.4 MB int2) aliases onto hA/hB region (51.2 MB): dead before spmm_w
    int2* tmp = (int2*)hraw;
    (void)ws_size; (void)off; (void)in_sizes; (void)n_in; (void)out_size;

    k_init<<<1, 512, 0, stream>>>(gcur);
    k_wconv<<<(IN_CH * OUT_CH / 2 + 255) / 256, 256, 0, stream>>>(W, Wh);
    kB<<<KB_GRID, KB_BLOCK, 0, stream>>>(frows, fcols, fvals, arows, acols, avals,
                                         gcur, tmp);
    k_scand<<<1, 512, 0, stream>>>(gcur, dstart);
    kC<<<NBUCK, 512, 0, stream>>>(gcur, dstart, tmp, pairs, S);

    spmm_w<<<N_NODES / 4, 256, 0, stream>>>(S, pairs, Wh, bias, hA);

    spmm_adj_hh<<<N_NODES / 4, 256, 0, stream>>>(S, pairs, hA, hB);
    spmm_adj_hh<<<N_NODES / 4, 256, 0, stream>>>(S, pairs, hB, hA);
    spmm_adj_hf<<<N_NODES / 4, 256, 0, stream>>>(S, pairs, hA, out);
}